// Round 1
// baseline (228.582 us; speedup 1.0000x reference)
//
#include <hip/hip_runtime.h>

// EMA recurrence: out[t] = a*x[t] + (1-a)*out[t-1] over T=4096 (contiguous),
// 8192 independent sequences [B=8, D=1024, T=4096] fp32.
//
// R6: supertile version. One wave per 512-float supertile (two chained
// 256-float tiles), halving wave count (131072 -> 65536) and halving the
// warm-up read amplification (12.5% -> 6.25%). Tile B's carry now comes
// exactly in-register from tile A (one extra broadcast shuffle) instead of
// a truncated warm-up scan -- strictly more accurate than R5 for odd tiles.
// Output stores are non-temporal: out is never re-read, and keeping x's
// lines in L2 is what the next supertile's warm-up load wants.
//
// Design recap (unchanged from R5):
//   - ZERO inter-wave dependency. Decay truncation: history older than 32
//     elements carries weight 0.6^32 ~ 8.4e-8 (abs threshold 5.5e-2).
//     Warm-up scan from h=0 over the previous 32 floats replaces the
//     sequential carry for supertile starts; supertile 0 of each sequence
//     uses the true hidden init.
//   - Per 256-tile: lane-local 4-elem scan + 3-step Kogge-Stone over lane
//     tails (weights b^4/b^8/b^16, truncated at b^32), exclusive carry
//     recovered algebraically (dropped term <= b^28 ~ 6e-7).

constexpr int STILES_PER_SEQ = 8;    // 4096 / 512

typedef float fvec4 __attribute__((ext_vector_type(4)));

__global__ __launch_bounds__(256) void ema_tile_kernel(
    const float* __restrict__ x,
    const float* __restrict__ h0,
    float* __restrict__ out,
    int ntiles)
{
    const int gtid = blockIdx.x * blockDim.x + threadIdx.x;
    const int w    = gtid >> 6;      // global supertile index = wave index
    const int lane = threadIdx.x & 63;
    if (w >= ntiles) return;

    const int sidx = w & (STILES_PER_SEQ - 1);
    const int seq  = w >> 3;

    const float a   = 0.4f;
    const float b   = 0.6f;
    const float b2  = b * b;
    const float b3  = b2 * b;
    const float b4  = b2 * b2;
    const float b8  = b4 * b4;
    const float b16 = b8 * b8;
    const float inv_b4 = 1.0f / b4;

    // Kogge-Stone step multipliers (0 where no source at that distance).
    const float m1 = (lane >= 1) ? b4  : 0.0f;
    const float m2 = (lane >= 2) ? b8  : 0.0f;
    const float m3 = (lane >= 4) ? b16 : 0.0f;
    // b^(4*lane): carry-in scale; underflows to ~0 beyond lane ~20 (truncation).
    const float pb4i = exp2f((float)(4 * lane) * -0.73696559416f);

    const float4* __restrict__ xp = (const float4*)x;
    fvec4* __restrict__ op        = (fvec4*)out;

    // All flat indices in size_t BEFORE pointer arithmetic.
    const size_t base = (size_t)w * 128;   // float4 units; 512 floats/wave

    // Supertile loads: two coalesced 1 KiB tiles, issued up-front.
    float4 vA = xp[base + (size_t)lane];          // floats [0,256)
    float4 vB = xp[base + 64 + (size_t)lane];     // floats [256,512)

    // Warm-up load: previous 32 floats, lanes 0-7 (wave-uniform outer branch).
    const bool has_warm = (sidx != 0);
    float4 wv = make_float4(0.f, 0.f, 0.f, 0.f);
    if (has_warm && lane < 8) {
        wv = xp[base - 8 + (size_t)lane];         // base >= 128 here
    }

    // --- lane-local scans (zero-init), 3 independent chains for ILP ---
    float a0 = a * vA.x;
    float a1 = fmaf(b, a0, a * vA.y);
    float a2 = fmaf(b, a1, a * vA.z);
    float a3 = fmaf(b, a2, a * vA.w);

    float c0 = a * vB.x;
    float c1 = fmaf(b, c0, a * vB.y);
    float c2 = fmaf(b, c1, a * vB.z);
    float c3 = fmaf(b, c2, a * vB.w);

    float d0 = a * wv.x;
    float d1 = fmaf(b, d0, a * wv.y);
    float d2 = fmaf(b, d1, a * wv.z);
    float d3 = fmaf(b, d2, a * wv.w);

    // --- Kogge-Stone over lane tails (distance k weight b^(4k), trunc b^32) ---
    float tA = a3, tB = c3, tw = d3, u;
    u = __shfl_up(tA, 1, 64); tA = fmaf(m1, u, tA);
    u = __shfl_up(tB, 1, 64); tB = fmaf(m1, u, tB);
    u = __shfl_up(tw, 1, 64); tw = fmaf(m1, u, tw);
    u = __shfl_up(tA, 2, 64); tA = fmaf(m2, u, tA);
    u = __shfl_up(tB, 2, 64); tB = fmaf(m2, u, tB);
    u = __shfl_up(tw, 2, 64); tw = fmaf(m2, u, tw);
    u = __shfl_up(tA, 4, 64); tA = fmaf(m3, u, tA);
    u = __shfl_up(tB, 4, 64); tB = fmaf(m3, u, tB);
    u = __shfl_up(tw, 4, 64); tw = fmaf(m3, u, tw);

    // --- incoming state at supertile start ---
    float h_in;
    if (has_warm) {
        h_in = __shfl(tw, 7, 64);    // tail of the 32 warm-up floats
    } else {
        h_in = h0[(size_t)seq];      // true initial hidden state (wave-uniform)
    }

    // --- tile A: exclusive carry recovered algebraically ---
    float eA = fmaf(pb4i, h_in, (tA - a3) * inv_b4);
    fvec4 oA;
    oA.x = fmaf(b , eA, a0);
    oA.y = fmaf(b2, eA, a1);
    oA.z = fmaf(b3, eA, a2);
    oA.w = fmaf(b4, eA, a3);

    // Exact carry into tile B: result at float 255 = lane 63's oA.w.
    float h_mid = __shfl(oA.w, 63, 64);

    // --- tile B ---
    float eB = fmaf(pb4i, h_mid, (tB - c3) * inv_b4);
    fvec4 oB;
    oB.x = fmaf(b , eB, c0);
    oB.y = fmaf(b2, eB, c1);
    oB.z = fmaf(b3, eB, c2);
    oB.w = fmaf(b4, eB, c3);

    // Non-temporal streaming stores: out is never re-read; don't evict x.
    __builtin_nontemporal_store(oA, &op[base + (size_t)lane]);
    __builtin_nontemporal_store(oB, &op[base + 64 + (size_t)lane]);
}

extern "C" void kernel_launch(void* const* d_in, const int* in_sizes, int n_in,
                              void* d_out, int out_size, void* d_ws, size_t ws_size,
                              hipStream_t stream) {
    const float* x  = (const float*)d_in[0];   // [8,1024,4096] fp32
    const float* h0 = (const float*)d_in[1];   // [8,1024,1]    fp32
    float* out = (float*)d_out;                // [8,1024,4096] fp32

    const int nseq   = in_sizes[1];            // 8192 sequences
    const int ntiles = nseq * STILES_PER_SEQ;  // 65536 waves
    const int block  = 256;                    // 4 waves/block
    const long long total = (long long)ntiles * 64;
    const int grid = (int)((total + block - 1) / block);  // 16384 blocks

    ema_tile_kernel<<<grid, block, 0, stream>>>(x, h0, out, ntiles);
}